// Round 8
// baseline (631.255 us; speedup 1.0000x reference)
//
#include <hip/hip_runtime.h>
#include <math.h>

#define N 4096
#define E 96
#define H 6
#define DH 16
#define G 64
#define CMAX 128          // max supported group size (mean 64, +8 sigma safe)
#define KSTR 20           // 20 floats = 80 B: 16B-aligned rows -> ds_read_b128; bank-uniform
#define NW 8              // waves per block
#define NT 512            // threads per block

// One block per (group, head, position-parity). Bucket build is DETERMINISTIC
// (ballot masks + prefix scan, no atomics) so both parity blocks of a (g,h)
// compute identical bucket arrays -> position parity partitions rows exactly.
// qkv is a SINGLE merged loop (k,v,q x 4 row-slots interleaved) so the
// compiler can pipeline the global feats loads instead of serializing them.
__global__ __launch_bounds__(NT, 6) void fused_kernel(const float* __restrict__ feats,
                                                      const int* __restrict__ grp,
                                                      const float* __restrict__ w_in,
                                                      const float* __restrict__ b_in,
                                                      const float* __restrict__ w_out,
                                                      const float* __restrict__ w_cls,
                                                      float* __restrict__ part) {
    __shared__ float wl[48 * 100];        // w_in head slice (48 cols x 96), stride 100
    __shared__ float kh[CMAX * KSTR];
    __shared__ float vh[CMAX * KSTR];     // fully zero-filled, then rows < cnt overwritten
    __shared__ float qh[64 * KSTR];       // own-parity q rows, compact index j = r>>1
    __shared__ float ps[NW * CMAX];       // per-wave softmax weights
    __shared__ int   bucket[CMAX];
    __shared__ unsigned long long smask[64];   // per-chunk membership masks
    __shared__ int   scount[64];
    __shared__ int   soffs[64];
    __shared__ float wfh[DH];             // head slice of folded classifier
    __shared__ int   scnt;

    int g  = blockIdx.x & 63;
    int hh = blockIdx.x >> 6;             // 0..11
    int h  = hh >> 1;
    int hb = hh & 1;                      // position parity this block owns
    int tid = threadIdx.x, lane = tid & 63, wv = tid >> 6;

    // ---- Phase A: per-chunk ballot masks (deterministic chunk->wave mapping)
    #pragma unroll
    for (int c8 = 0; c8 < 8; ++c8) {
        int cc = wv * 8 + c8;                       // chunk 0..63
        bool mt = (grp[(cc << 6) + lane] == g);     // coalesced, L2-hot
        unsigned long long mask = __ballot(mt);
        if (lane == 0) { smask[cc] = mask; scount[cc] = __popcll(mask); }
    }

    // ---- stage w_in slice: {q,k,v} x 16 cols for this head
    for (int idx = tid; idx < 48 * 24; idx += NT) {
        int ci = idx / 24, j = idx % 24;
        int pp = ci >> 4, dd = ci & 15;
        int gcol = pp * E + h * DH + dd;
        *(float4*)(wl + ci * 100 + j * 4) = *(const float4*)(w_in + gcol * E + j * 4);
    }

    // ---- head slice of folded classifier: wfh[dd] = sum_u w_cls[u]*w_out[u][h*16+dd]
    if (wv == 7) {
        int dd = lane & 15, u4 = lane >> 4;
        float s = 0.f;
        for (int u = u4 * 24; u < u4 * 24 + 24; ++u)
            s += w_cls[u] * w_out[u * E + h * DH + dd];
        s += __shfl_xor(s, 16, 64);
        s += __shfl_xor(s, 32, 64);
        if (lane < DH) wfh[lane] = s;
    }
    __syncthreads();

    // ---- Phase B: wave 0 exclusive-scans chunk counts; waves 1..7 zero-fill vh
    if (wv == 0) {
        int v = scount[lane];
        int x = v;
        #pragma unroll
        for (int o = 1; o < 64; o <<= 1) {
            int y = __shfl_up(x, o, 64);
            if (lane >= o) x += y;
        }
        soffs[lane] = x - v;
        if (lane == 63) scnt = x;
    } else {
        for (int idx = tid - 64; idx < CMAX * KSTR; idx += NT - 64) vh[idx] = 0.f;
    }
    __syncthreads();

    int cnt = scnt; if (cnt > CMAX) cnt = CMAX;

    // ---- Phase C: deterministic scatter (identical in both parity blocks)
    #pragma unroll
    for (int c8 = 0; c8 < 8; ++c8) {
        int cc = wv * 8 + c8;
        unsigned long long mask = smask[cc];
        if ((mask >> lane) & 1ULL) {
            int pos = soffs[cc] + __popcll(mask & ((1ULL << lane) - 1ULL));
            if (pos < CMAX) bucket[pos] = (cc << 6) + lane;
        }
    }
    __syncthreads();

    // ---- merged qkv: thread (d = tid&15, rr = tid>>4); 4 row-slots interleaved
    int d = tid & 15, rr = tid >> 4;      // rr 0..31
    float bq = b_in[h * DH + d];
    float bk = b_in[E + h * DH + d];
    float bv = b_in[2 * E + h * DH + d];
    const float4* wq  = (const float4*)(wl + d * 100);
    const float4* wk  = (const float4*)(wl + (16 + d) * 100);
    const float4* wvp = (const float4*)(wl + (32 + d) * 100);

    int s0 = rr, s1 = rr + 32, s2 = rr + 64, s3 = rr + 96;
    const float4* f0 = (const float4*)(feats + (s0 < cnt ? bucket[s0] : 0) * E);
    const float4* f1 = (const float4*)(feats + (s1 < cnt ? bucket[s1] : 0) * E);
    const float4* f2 = (const float4*)(feats + (s2 < cnt ? bucket[s2] : 0) * E);
    const float4* f3 = (const float4*)(feats + (s3 < cnt ? bucket[s3] : 0) * E);

    float q0 = 0.f, q1 = 0.f, q2 = 0.f, q3 = 0.f;
    float k0 = 0.f, k1 = 0.f, k2 = 0.f, k3 = 0.f;
    float v0 = 0.f, v1 = 0.f, v2 = 0.f, v3 = 0.f;
    #pragma unroll
    for (int e4 = 0; e4 < 24; ++e4) {
        float4 a = wq[e4], b = wk[e4], c = wvp[e4];
        float4 x0 = f0[e4], x1 = f1[e4], x2 = f2[e4], x3 = f3[e4];
        q0 += x0.x*a.x + x0.y*a.y + x0.z*a.z + x0.w*a.w;
        k0 += x0.x*b.x + x0.y*b.y + x0.z*b.z + x0.w*b.w;
        v0 += x0.x*c.x + x0.y*c.y + x0.z*c.z + x0.w*c.w;
        q1 += x1.x*a.x + x1.y*a.y + x1.z*a.z + x1.w*a.w;
        k1 += x1.x*b.x + x1.y*b.y + x1.z*b.z + x1.w*b.w;
        v1 += x1.x*c.x + x1.y*c.y + x1.z*c.z + x1.w*c.w;
        q2 += x2.x*a.x + x2.y*a.y + x2.z*a.z + x2.w*a.w;
        k2 += x2.x*b.x + x2.y*b.y + x2.z*b.z + x2.w*b.w;
        v2 += x2.x*c.x + x2.y*c.y + x2.z*c.z + x2.w*c.w;
        q3 += x3.x*a.x + x3.y*a.y + x3.z*a.z + x3.w*a.w;
        k3 += x3.x*b.x + x3.y*b.y + x3.z*b.z + x3.w*b.w;
        v3 += x3.x*c.x + x3.y*c.y + x3.z*c.z + x3.w*c.w;
    }
    if (s0 < cnt) { kh[s0*KSTR+d] = k0+bk; vh[s0*KSTR+d] = v0+bv;
                    if ((s0 & 1) == hb) qh[(s0>>1)*KSTR+d] = (q0+bq)*0.25f; }
    if (s1 < cnt) { kh[s1*KSTR+d] = k1+bk; vh[s1*KSTR+d] = v1+bv;
                    if ((s1 & 1) == hb) qh[(s1>>1)*KSTR+d] = (q1+bq)*0.25f; }
    if (s2 < cnt) { kh[s2*KSTR+d] = k2+bk; vh[s2*KSTR+d] = v2+bv;
                    if ((s2 & 1) == hb) qh[(s2>>1)*KSTR+d] = (q2+bq)*0.25f; }
    if (s3 < cnt) { kh[s3*KSTR+d] = k3+bk; vh[s3*KSTR+d] = v3+bv;
                    if ((s3 & 1) == hb) qh[(s3>>1)*KSTR+d] = (q3+bq)*0.25f; }
    __syncthreads();

    // ---- attention: wave wv handles compact rows j = wv, wv+8, ...
    for (int j = wv; 2 * j + hb < cnt; j += NW) {
        int r = 2 * j + hb;
        const float4* q4 = (const float4*)(qh + j * KSTR);      // wave-uniform broadcast
        float4 qa = q4[0], qb = q4[1], qc = q4[2], qd = q4[3];

        const float4* k4 = (const float4*)(kh + lane * KSTR);
        float4 ka = k4[0], kb = k4[1], kc = k4[2], kd = k4[3];
        float d0 = qa.x*ka.x + qa.y*ka.y + qa.z*ka.z + qa.w*ka.w;
        float d1 = qb.x*kb.x + qb.y*kb.y + qb.z*kb.z + qb.w*kb.w;
        float d2 = qc.x*kc.x + qc.y*kc.y + qc.z*kc.z + qc.w*kc.w;
        float d3 = qd.x*kd.x + qd.y*kd.y + qd.z*kd.z + qd.w*kd.w;
        float a0 = (d0 + d1) + (d2 + d3);
        float s0v = (lane < cnt) ? a0 : -INFINITY;
        float s1v = -INFINITY;
        if (cnt > 64) {
            const float4* k4b = (const float4*)(kh + (64 + lane) * KSTR);
            float4 ea = k4b[0], eb = k4b[1], ec = k4b[2], ed = k4b[3];
            float e0 = qa.x*ea.x + qa.y*ea.y + qa.z*ea.z + qa.w*ea.w;
            float e1 = qb.x*eb.x + qb.y*eb.y + qb.z*eb.z + qb.w*eb.w;
            float e2 = qc.x*ec.x + qc.y*ec.y + qc.z*ec.z + qc.w*ec.w;
            float e3 = qd.x*ed.x + qd.y*ed.y + qd.z*ed.z + qd.w*ed.w;
            float a1 = (e0 + e1) + (e2 + e3);
            s1v = (64 + lane < cnt) ? a1 : -INFINITY;
        }

        float m = fmaxf(s0v, s1v);
        #pragma unroll
        for (int o = 32; o >= 1; o >>= 1) m = fmaxf(m, __shfl_xor(m, o, 64));
        float p0 = __expf(s0v - m);                     // masked lanes -> 0
        float p1 = (cnt > 64) ? __expf(s1v - m) : 0.f;
        float l = p0 + p1;
        #pragma unroll
        for (int o = 32; o >= 1; o >>= 1) l += __shfl_xor(l, o, 64);
        ps[wv * CMAX + lane] = p0;
        ps[wv * CMAX + 64 + lane] = p1;

        // PV: fixed-trip, fully unrolled; ps==0 / vh==0 cover padding
        int mm4 = lane >> 4, dd = lane & 15;
        float acc = 0.f;
        #pragma unroll
        for (int k = 0; k < 16; ++k) {
            int m2 = mm4 + 4 * k;
            acc += ps[wv * CMAX + m2] * vh[m2 * KSTR + dd];
        }
        if (cnt > 64) {
            #pragma unroll
            for (int k = 16; k < 32; ++k) {
                int m2 = mm4 + 4 * k;
                acc += ps[wv * CMAX + m2] * vh[m2 * KSTR + dd];
            }
        }
        acc += __shfl_xor(acc, 16, 64);
        acc += __shfl_xor(acc, 32, 64);

        // partial logit for this head
        float pt = (acc / l) * wfh[dd];
        pt += __shfl_xor(pt, 1, 64);
        pt += __shfl_xor(pt, 2, 64);
        pt += __shfl_xor(pt, 4, 64);
        pt += __shfl_xor(pt, 8, 64);
        if (lane == 0) part[bucket[r] * 8 + h] = pt;    // exactly-once write, no atomic
    }
}

// ---------------- K2: sum 6 head partials + folded bias, sigmoid
__global__ __launch_bounds__(512) void sigmoid_kernel(const float* __restrict__ part,
                                                      const float* __restrict__ w_cls,
                                                      const float* __restrict__ b_out,
                                                      const float* __restrict__ b_cls,
                                                      float* __restrict__ out) {
    __shared__ float sbias;
    int tid = threadIdx.x;
    if (tid < 64) {
        float s = w_cls[tid] * b_out[tid];
        if (tid < 32) s += w_cls[tid + 64] * b_out[tid + 64];
        #pragma unroll
        for (int o = 32; o >= 1; o >>= 1) s += __shfl_xor(s, o, 64);
        if (tid == 0) sbias = s + b_cls[0];
    }
    __syncthreads();
    int i = blockIdx.x * 512 + tid;
    const float4* p = (const float4*)(part + i * 8);
    float4 u = p[0], v = p[1];
    float s = u.x + u.y + u.z + u.w + v.x + v.y + sbias;
    out[i] = 1.f / (1.f + __expf(-s));
}

extern "C" void kernel_launch(void* const* d_in, const int* in_sizes, int n_in,
                              void* d_out, int out_size, void* d_ws, size_t ws_size,
                              hipStream_t stream) {
    const float* feats = (const float*)d_in[0];
    const int*   grp   = (const int*)  d_in[1];
    const float* w_in  = (const float*)d_in[2];
    const float* b_in  = (const float*)d_in[3];
    const float* w_out = (const float*)d_in[4];
    const float* b_out = (const float*)d_in[5];
    const float* w_cls = (const float*)d_in[6];
    const float* b_cls = (const float*)d_in[7];
    float* out = (float*)d_out;

    float* part = (float*)d_ws;           // N*8 floats, every (row,head<6) slot written

    fused_kernel<<<G * H * 2, NT, 0, stream>>>(feats, grp, w_in, b_in, w_out, w_cls, part);
    sigmoid_kernel<<<N / 512, 512, 0, stream>>>(part, w_cls, b_out, b_cls, out);
}